// Round 16
// baseline (407.710 us; speedup 1.0000x reference)
//
#include <hip/hip_runtime.h>
#include <hip/hip_bf16.h>
#include <hip/hip_fp16.h>

// TemporalGNN: GRU's H stays zero => R dead, timesteps independent.
// out[b,n,:] = relu( sum_t p_t*(1-Z_t)*Ht_t ) @ W_out + b_out
// R16 = R15 with (1) CSR window read as uniform int4 pairs (s_load merge:
// one scalar round-trip per 8 edges), (2) next-task bounds prefetched under
// the MFMA/EPI compute phase, (3) kB1+kB3 merged into one scan kernel.

#define FDIM 32
#define TDIM 12
#define ODIM 64
#define BDIM 4
#define SCAN_TILE 1024

typedef _Float16 half8v __attribute__((ext_vector_type(8)));
typedef float float4v __attribute__((ext_vector_type(4)));

// ---- fused setup kernel A: [0,cvtB) cvt, [cvtB,cvtB+cntB) count, last prep ----
__global__ __launch_bounds__(256) void kA(
    const float4* __restrict__ Xin, uint2* __restrict__ Xh, int n4, int cvtB,
    const int* __restrict__ dstE, int* __restrict__ counts, int E, int cntB,
    const float* __restrict__ Wg_z, const float* __restrict__ bg_z,
    const float* __restrict__ Wl_z, const float* __restrict__ bl_z,
    const float* __restrict__ Wg_h, const float* __restrict__ bg_h,
    const float* __restrict__ Wl_h, const float* __restrict__ bl_h,
    const float* __restrict__ att,
    float* __restrict__ Wz, float* __restrict__ bz,
    float* __restrict__ Wh, float* __restrict__ bh,
    float* __restrict__ probs) {
    const int bid = blockIdx.x;
    const int tid = threadIdx.x;
    if (bid < cvtB) {
        int i = bid * 256 + tid;
        const int stride = cvtB * 256;
        for (; i < n4; i += stride) {
            const float4 v = Xin[i];
            __half2 h0 = __floats2half2_rn(v.x, v.y);
            __half2 h1 = __floats2half2_rn(v.z, v.w);
            uint2 u;
            u.x = *reinterpret_cast<unsigned*>(&h0);
            u.y = *reinterpret_cast<unsigned*>(&h1);
            Xh[i] = u;
        }
    } else if (bid < cvtB + cntB) {
        int e = (bid - cvtB) * 256 + tid;
        if (e < E) atomicAdd(&counts[dstE[e]], 1);
    } else {
        for (int i = tid; i < FDIM * ODIM; i += 256) {
            int f = i >> 6, o = i & 63;
            float az = 0.f, ah = 0.f;
            for (int k = 0; k < ODIM; k++) {
                az += Wg_z[f * ODIM + k] * Wl_z[k * ODIM + o];
                ah += Wg_h[f * ODIM + k] * Wl_h[k * ODIM + o];
            }
            Wz[i] = az;
            Wh[i] = ah;
        }
        if (tid < ODIM) {
            float az = bl_z[tid], ah = bl_h[tid];
            for (int k = 0; k < ODIM; k++) {
                az += bg_z[k] * Wl_z[k * ODIM + tid];
                ah += bg_h[k] * Wl_h[k * ODIM + tid];
            }
            bz[tid] = az;
            bh[tid] = ah;
        }
        if (tid == 0) {
            float m = -1e30f;
            for (int t = 0; t < TDIM; t++) m = fmaxf(m, att[t]);
            float e[TDIM], s = 0.f;
            for (int t = 0; t < TDIM; t++) { e[t] = expf(att[t] - m); s += e[t]; }
            for (int t = 0; t < TDIM; t++) probs[t] = e[t] / s;
        }
    }
}

// ---- single-pass scan: each block re-reduces all prior tiles itself, then
//      scans its own tile and writes offsets/dis/fill/self-edges. ----
__global__ __launch_bounds__(256) void kB(const int* __restrict__ counts, int N,
                                          int* __restrict__ offsets,
                                          float* __restrict__ dis,
                                          int* __restrict__ fill,
                                          int2* __restrict__ csr, int E) {
    __shared__ int sBase;
    __shared__ int wsum[4];
    const int tid = threadIdx.x;
    const int blk = blockIdx.x;
    const int lane = tid & 63;
    const int wv = tid >> 6;

    // parallel reduce of counts[0 .. blk*TILE) across the whole block
    int pre = 0;
    const int preEnd = blk * SCAN_TILE;
    for (int i = tid; i < preEnd; i += 256) pre += counts[i] + 1;
    for (int off = 1; off < 64; off <<= 1) pre += __shfl_xor(pre, off, 64);
    if (lane == 0) wsum[wv] = pre;
    __syncthreads();
    if (tid == 0) sBase = wsum[0] + wsum[1] + wsum[2] + wsum[3];
    __syncthreads();

    const int i0 = blk * SCAN_TILE + tid * 4;
    const int e0 = (i0 + 0 < N) ? counts[i0 + 0] + 1 : 0;
    const int e1 = (i0 + 1 < N) ? counts[i0 + 1] + 1 : 0;
    const int e2 = (i0 + 2 < N) ? counts[i0 + 2] + 1 : 0;
    const int e3 = (i0 + 3 < N) ? counts[i0 + 3] + 1 : 0;
    const int s = e0 + e1 + e2 + e3;
    int inc = s;
    for (int off = 1; off < 64; off <<= 1) {
        int t = __shfl_up(inc, off, 64);
        if (lane >= off) inc += t;
    }
    __syncthreads();                 // wsum reuse
    if (lane == 63) wsum[wv] = inc;
    __syncthreads();
    int wbase = 0;
    for (int j = 0; j < wv; j++) wbase += wsum[j];
    int base = sBase + wbase + inc - s;

    const int ee[4] = {e0, e1, e2, e3};
#pragma unroll
    for (int k = 0; k < 4; k++) {
        const int i = i0 + k;
        if (i < N) {
            offsets[i] = base;
            const float d = 1.0f / sqrtf((float)ee[k]);
            dis[i] = d;
            fill[i] = 1;
            const float nm = d * d;
            __half2 mh = __floats2half2_rn(nm, nm);
            csr[base] = make_int2(i, *(int*)&mh);
            base += ee[k];
        }
    }
    if (blk == 0 && tid == 0) offsets[N] = E + N;
}

__global__ void k_scatter(const int* __restrict__ src, const int* __restrict__ dst,
                          const int* __restrict__ offsets, int* __restrict__ fill,
                          const float* __restrict__ dis,
                          int2* __restrict__ csr, int E) {
    int e = blockIdx.x * 256 + threadIdx.x;
    if (e < E) {
        int s = src[e], d = dst[e];
        int pos = offsets[d] + atomicAdd(&fill[d], 1);
        float nm = dis[s] * dis[d];
        __half2 mh = __floats2half2_rn(nm, nm);
        csr[pos] = make_int2(s, *(int*)&mh);
    }
}

__device__ __forceinline__ float sigm(float x) { return 1.f / (1.f + __expf(-x)); }
__device__ __forceinline__ float tanhfast(float x) { return 1.f - 2.f / (1.f + __expf(2.f * x)); }

#define HPACC(mhI, v, hs0, hs1, hs2, hs3)                                      \
    {                                                                          \
        int mi_ = (mhI);                                                       \
        __half2 mh_ = *(__half2*)&mi_;                                         \
        hs0 = __hfma2(mh_, *(__half2*)&(v).x, hs0);                            \
        hs1 = __hfma2(mh_, *(__half2*)&(v).y, hs1);                            \
        hs2 = __hfma2(mh_, *(__half2*)&(v).z, hs2);                            \
        hs3 = __hfma2(mh_, *(__half2*)&(v).w, hs3);                            \
    }

#define HFLUSH(hs0, hs1, hs2, hs3)                                             \
    {                                                                          \
        float2 t_;                                                             \
        t_ = __half22float2(hs0); a0 += t_.x; a1 += t_.y;                      \
        t_ = __half22float2(hs1); a2 += t_.x; a3 += t_.y;                      \
        t_ = __half22float2(hs2); a4 += t_.x; a5 += t_.y;                      \
        t_ = __half22float2(hs3); a6 += t_.x; a7 += t_.y;                      \
        hs0 = hzero; hs1 = hzero; hs2 = hzero; hs3 = hzero;                    \
    }

#define LOADB(dst, Wsrc, jt)                                                   \
    {                                                                          \
        _Pragma("unroll") for (int r_ = 0; r_ < 8; r_++)                       \
            dst[r_] = (_Float16)Wsrc[(kg * 8 + r_) * ODIM + (jt) * 16 + c];    \
    }

#define EPI(qv, dzv, dhv, bzv, bhv)                                            \
    {                                                                          \
        float s_ = 0.f;                                                        \
        {  const float zf_ = dzv[0] + bzv, hf_ = dhv[0] + bhv;                 \
           const float u_ = __expf(-zf_), v_ = __expf(2.f * hf_);              \
           s_ += pr0 * u_ * (v_ - 1.f) *                                       \
                 __builtin_amdgcn_rcpf((1.f + u_) * (1.f + v_)); }             \
        {  const float zf_ = dzv[1] + bzv, hf_ = dhv[1] + bhv;                 \
           const float u_ = __expf(-zf_), v_ = __expf(2.f * hf_);              \
           s_ += pr1 * u_ * (v_ - 1.f) *                                       \
                 __builtin_amdgcn_rcpf((1.f + u_) * (1.f + v_)); }             \
        {  const float zf_ = dzv[2] + bzv, hf_ = dhv[2] + bhv;                 \
           const float u_ = __expf(-zf_), v_ = __expf(2.f * hf_);              \
           s_ += pr2 * u_ * (v_ - 1.f) *                                       \
                 __builtin_amdgcn_rcpf((1.f + u_) * (1.f + v_)); }             \
        {  const float zf_ = dzv[3] + bzv, hf_ = dhv[3] + bhv;                 \
           const float u_ = __expf(-zf_), v_ = __expf(2.f * hf_);              \
           s_ += pr3 * u_ * (v_ - 1.f) *                                       \
                 __builtin_amdgcn_rcpf((1.f + u_) * (1.f + v_)); }             \
        s_ += __shfl_xor(s_, 16, 64);                                          \
        s_ += __shfl_xor(s_, 32, 64);                                          \
        qv = s_;                                                               \
    }

// Wave-independent main kernel + MFMA gates + MFMA readout + wide scalar CSR.
__global__ __launch_bounds__(256, 4) void k_main_w(
    const uint4* __restrict__ Xh, const int* __restrict__ offs,
    const int2* __restrict__ csr,
    const float* __restrict__ Wz, const float* __restrict__ bz,
    const float* __restrict__ Wh, const float* __restrict__ bh,
    const float* __restrict__ probs, const float* __restrict__ Wout,
    const float* __restrict__ bout, float* __restrict__ out, int N) {
    __shared__ float sY[4][16 * 36 + 4];   // [t][f] padded stride 36

    const int tid = threadIdx.x;
    const int wv = tid >> 6;
    const int lane = tid & 63;
    const int lanec = lane < 47 ? lane : 47;
    const int c = lane & 15;
    const int kg = lane >> 4;

    half8v wzf0, wzf1, wzf2, wzf3, whf0, whf1, whf2, whf3;
    LOADB(wzf0, Wz, 0) LOADB(wzf1, Wz, 1) LOADB(wzf2, Wz, 2) LOADB(wzf3, Wz, 3)
    LOADB(whf0, Wh, 0) LOADB(whf1, Wh, 1) LOADB(whf2, Wh, 2) LOADB(whf3, Wh, 3)
    half8v wo0, wo1;
#pragma unroll
    for (int r_ = 0; r_ < 8; r_++) {
        wo0[r_] = (_Float16)((c < TDIM) ? Wout[(kg * 8 + r_) * TDIM + c] : 0.f);
        wo1[r_] = (_Float16)((c < TDIM) ? Wout[(32 + kg * 8 + r_) * TDIM + c] : 0.f);
    }
    const float bz0 = bz[c], bz1 = bz[16 + c], bz2 = bz[32 + c], bz3 = bz[48 + c];
    const float bh0 = bh[c], bh1 = bh[16 + c], bh2 = bh[32 + c], bh3 = bh[48 + c];
    const float pr0 = (kg * 4 + 0 < TDIM) ? probs[kg * 4 + 0] : 0.f;
    const float pr1 = (kg * 4 + 1 < TDIM) ? probs[kg * 4 + 1] : 0.f;
    const float pr2 = (kg * 4 + 2 < TDIM) ? probs[kg * 4 + 2] : 0.f;
    const float pr3 = (kg * 4 + 3 < TDIM) ? probs[kg * 4 + 3] : 0.f;
    const float bo = (lane < TDIM) ? bout[lane] : 0.f;
    const __half2 hzero = __float2half2_rn(0.f);
    const int4* __restrict__ csr4 = (const int4*)csr;

    float* __restrict__ sy = sY[wv];
    const int strideT = gridDim.x * 4;
    const int totalTasks = N * BDIM;

    int task0 = blockIdx.x * 4 + wv;
    if (task0 >= totalTasks) return;
    int b = task0 / N;
    int n = task0 - b * N;

    // bounds for the first task
    int begS, endS;
    {
        const int ns0 = __builtin_amdgcn_readfirstlane(n);
        begS = __builtin_amdgcn_readfirstlane(offs[ns0]);
        endS = __builtin_amdgcn_readfirstlane(offs[ns0 + 1]);
    }

    while (true) {
        const int bs = __builtin_amdgcn_readfirstlane(b);
        const unsigned rowB = (unsigned)bs * (unsigned)N;

        // ---- gather: wide scalar CSR stream, fp16 packed accumulate ----
        float a0 = 0.f, a1 = 0.f, a2 = 0.f, a3 = 0.f,
              a4 = 0.f, a5 = 0.f, a6 = 0.f, a7 = 0.f;
        __half2 hA0 = hzero, hA1 = hzero, hA2 = hzero, hA3 = hzero;
        __half2 hB0 = hzero, hB1 = hzero, hB2 = hzero, hB3 = hzero;
        int j = begS;
        if ((j & 1) && j < endS) {   // peel to int4 alignment
            const int2 e = csr[j];
            const uint4 xv = Xh[(rowB + (unsigned)e.x) * 48u + lanec];
            HPACC(e.y, xv, hA0, hA1, hA2, hA3);
            ++j;
        }
        for (; j + 8 <= endS; j += 8) {
            const int jh = j >> 1;
            const int4 p0 = csr4[jh + 0];   // 2 edges each; 4 adjacent uniform
            const int4 p1 = csr4[jh + 1];   // int4 loads -> merged s_load
            const int4 p2 = csr4[jh + 2];
            const int4 p3 = csr4[jh + 3];
            const uint4 x0 = Xh[(rowB + (unsigned)p0.x) * 48u + lanec];
            const uint4 x1 = Xh[(rowB + (unsigned)p0.z) * 48u + lanec];
            const uint4 x2 = Xh[(rowB + (unsigned)p1.x) * 48u + lanec];
            const uint4 x3 = Xh[(rowB + (unsigned)p1.z) * 48u + lanec];
            const uint4 x4 = Xh[(rowB + (unsigned)p2.x) * 48u + lanec];
            const uint4 x5 = Xh[(rowB + (unsigned)p2.z) * 48u + lanec];
            const uint4 x6 = Xh[(rowB + (unsigned)p3.x) * 48u + lanec];
            const uint4 x7 = Xh[(rowB + (unsigned)p3.z) * 48u + lanec];
            HPACC(p0.y, x0, hA0, hA1, hA2, hA3);
            HPACC(p0.w, x1, hA0, hA1, hA2, hA3);
            HPACC(p1.y, x2, hA0, hA1, hA2, hA3);
            HPACC(p1.w, x3, hA0, hA1, hA2, hA3);
            HPACC(p2.y, x4, hB0, hB1, hB2, hB3);
            HPACC(p2.w, x5, hB0, hB1, hB2, hB3);
            HPACC(p3.y, x6, hB0, hB1, hB2, hB3);
            HPACC(p3.w, x7, hB0, hB1, hB2, hB3);
            HFLUSH(hA0, hA1, hA2, hA3);
            HFLUSH(hB0, hB1, hB2, hB3);
        }
        for (; j < endS; ++j) {
            const int2 e = csr[j];
            const uint4 xv = Xh[(rowB + (unsigned)e.x) * 48u + lanec];
            HPACC(e.y, xv, hA0, hA1, hA2, hA3);
        }
        HFLUSH(hA0, hA1, hA2, hA3);

        // ---- prefetch next task's bounds (hidden under compute below) ----
        int nn = n + strideT, nb = b;
        if (nn >= N) { nn -= N; nb++; }
        const bool hasNext = nb < BDIM;
        int begN = 0, endN = 0;
        if (hasNext) {
            const int nns = __builtin_amdgcn_readfirstlane(nn);
            begN = __builtin_amdgcn_readfirstlane(offs[nns]);
            endN = __builtin_amdgcn_readfirstlane(offs[nns + 1]);
        }

        // ---- deposit Y to LDS transposed [t][f] (stride 36) ----
        if (lane < 48) {
            int flat = lane * 8;               // = f*12 + t
            int f = flat / 12;
            int t = flat - f * 12;
#pragma unroll
            for (int k = 0; k < 8; k++) {
                float av = (k == 0) ? a0 : (k == 1) ? a1 : (k == 2) ? a2 :
                           (k == 3) ? a3 : (k == 4) ? a4 : (k == 5) ? a5 :
                           (k == 6) ? a6 : a7;
                sy[t * 36 + f] = av;
                t++;
                if (t == TDIM) { t = 0; f++; }
            }
        }

        // ---- A-frag: row=c (t), k=kg*8+j (f) ----
        half8v af;
        if (c < TDIM) {
            const float4* yp = (const float4*)&sy[c * 36 + kg * 8];
            const float4 y0 = yp[0];
            const float4 y1 = yp[1];
            af[0] = (_Float16)y0.x; af[1] = (_Float16)y0.y;
            af[2] = (_Float16)y0.z; af[3] = (_Float16)y0.w;
            af[4] = (_Float16)y1.x; af[5] = (_Float16)y1.y;
            af[6] = (_Float16)y1.z; af[7] = (_Float16)y1.w;
        } else {
            af[0] = (_Float16)0.f; af[1] = (_Float16)0.f;
            af[2] = (_Float16)0.f; af[3] = (_Float16)0.f;
            af[4] = (_Float16)0.f; af[5] = (_Float16)0.f;
            af[6] = (_Float16)0.f; af[7] = (_Float16)0.f;
        }

        // ---- gates via MFMA ----
        const float4v zero4 = {0.f, 0.f, 0.f, 0.f};
        float4v dz0 = __builtin_amdgcn_mfma_f32_16x16x32_f16(af, wzf0, zero4, 0, 0, 0);
        float4v dz1 = __builtin_amdgcn_mfma_f32_16x16x32_f16(af, wzf1, zero4, 0, 0, 0);
        float4v dz2 = __builtin_amdgcn_mfma_f32_16x16x32_f16(af, wzf2, zero4, 0, 0, 0);
        float4v dz3 = __builtin_amdgcn_mfma_f32_16x16x32_f16(af, wzf3, zero4, 0, 0, 0);
        float4v dh0 = __builtin_amdgcn_mfma_f32_16x16x32_f16(af, whf0, zero4, 0, 0, 0);
        float4v dh1 = __builtin_amdgcn_mfma_f32_16x16x32_f16(af, whf1, zero4, 0, 0, 0);
        float4v dh2 = __builtin_amdgcn_mfma_f32_16x16x32_f16(af, whf2, zero4, 0, 0, 0);
        float4v dh3 = __builtin_amdgcn_mfma_f32_16x16x32_f16(af, whf3, zero4, 0, 0, 0);

        // ---- epilogue: per-o weighted gate sum ----
        float q0, q1, q2, q3;
        EPI(q0, dz0, dh0, bz0, bh0)
        EPI(q1, dz1, dh1, bz1, bh1)
        EPI(q2, dz2, dh2, bz2, bh2)
        EPI(q3, dz3, dh3, bz3, bh3)
        const float accOwn = (kg == 0) ? q0 : (kg == 1) ? q1 : (kg == 2) ? q2 : q3;

        // ---- readout GEMV on MFMA ----
        const float r = fmaxf(accOwn, 0.f);
        half8v ra0, ra1;
#pragma unroll
        for (int j2 = 0; j2 < 8; j2++) {
            ra0[j2] = (_Float16)__shfl(r, (kg << 3) + j2, 64);
            ra1[j2] = (_Float16)__shfl(r, 32 + (kg << 3) + j2, 64);
        }
        float4v dro = __builtin_amdgcn_mfma_f32_16x16x32_f16(ra0, wo0, zero4, 0, 0, 0);
        dro = __builtin_amdgcn_mfma_f32_16x16x32_f16(ra1, wo1, dro, 0, 0, 0);
        if (lane < TDIM)
            out[(rowB + (unsigned)n) * TDIM + lane] = dro[0] + bo;

        // ---- advance task (bounds already prefetched) ----
        if (!hasNext) break;
        b = nb; n = nn; begS = begN; endS = endN;
    }
}

// fp32 fallback (no fp16 workspace): consumes self-inclusive csr (half2 norms).
__global__ __launch_bounds__(384) void k_main_f(
    const float* __restrict__ X, const int* __restrict__ offsets,
    const int2* __restrict__ csr, const float* __restrict__ dis,
    const float* __restrict__ Wz, const float* __restrict__ bz,
    const float* __restrict__ Wh, const float* __restrict__ bh,
    const float* __restrict__ probs, const float* __restrict__ Wout,
    const float* __restrict__ bout, float* __restrict__ out, int N) {
    const int tid = threadIdx.x;
    const int lane = tid & 63;

    __shared__ float4 sY4[BDIM][96];
    __shared__ float sAcc[BDIM][ODIM];
    __shared__ float sWout[ODIM * TDIM];
    __shared__ float sBout[TDIM];

    for (int i = tid; i < ODIM * TDIM; i += 384) sWout[i] = Wout[i];
    if (tid < TDIM) sBout[tid] = bout[tid];

    const int o = tid & 63;
    const int w = tid >> 6;
    float wzr[FDIM], whr[FDIM];
#pragma unroll
    for (int f = 0; f < FDIM; f++) {
        wzr[f] = Wz[f * ODIM + o];
        whr[f] = Wh[f * ODIM + o];
    }
    const float bzo = bz[o], bho = bh[o];
    const int t0 = w, t1 = w + 6;
    const float p0 = probs[t0], p1 = probs[t1];

    const int b = tid / 96;
    const int q = tid - b * 96;
    const float4* __restrict__ Xq = (const float4*)X;
    const unsigned rowBase = (unsigned)b * (unsigned)N;

    for (int n = blockIdx.x; n < N; n += gridDim.x) {
        if (tid < BDIM * ODIM) ((float*)sAcc)[tid] = 0.f;

        const int beg = offsets[n], end = offsets[n + 1];
        float4 A0 = make_float4(0.f, 0.f, 0.f, 0.f);
        float4 A1 = A0, A2 = A0, A3 = A0;

        for (int ebase = beg; ebase < end; ebase += 64) {
            const int cnt2 = min(64, end - ebase);
            int esrc = 0;
            float enm = 0.f;
            if (ebase + lane < end) {
                const int2 e = csr[ebase + lane];
                esrc = e.x;
                int ey = e.y;
                enm = __half22float2(*(__half2*)&ey).x;
            }
            int j = 0;
            for (; j + 4 <= cnt2; j += 4) {
                const int s0 = __shfl(esrc, j + 0, 64), s1 = __shfl(esrc, j + 1, 64);
                const int s2 = __shfl(esrc, j + 2, 64), s3 = __shfl(esrc, j + 3, 64);
                const float m0 = __shfl(enm, j + 0, 64), m1 = __shfl(enm, j + 1, 64);
                const float m2 = __shfl(enm, j + 2, 64), m3 = __shfl(enm, j + 3, 64);
                const float4 u0 = Xq[(rowBase + s0) * 96u + q];
                const float4 u1 = Xq[(rowBase + s1) * 96u + q];
                const float4 u2 = Xq[(rowBase + s2) * 96u + q];
                const float4 u3 = Xq[(rowBase + s3) * 96u + q];
                A0.x += m0 * u0.x; A0.y += m0 * u0.y; A0.z += m0 * u0.z; A0.w += m0 * u0.w;
                A1.x += m1 * u1.x; A1.y += m1 * u1.y; A1.z += m1 * u1.z; A1.w += m1 * u1.w;
                A2.x += m2 * u2.x; A2.y += m2 * u2.y; A2.z += m2 * u2.z; A2.w += m2 * u2.w;
                A3.x += m3 * u3.x; A3.y += m3 * u3.y; A3.z += m3 * u3.z; A3.w += m3 * u3.w;
            }
            for (; j < cnt2; j++) {
                const int s = __shfl(esrc, j, 64);
                const float m = __shfl(enm, j, 64);
                const float4 u = Xq[(rowBase + s) * 96u + q];
                A0.x += m * u.x; A0.y += m * u.y; A0.z += m * u.z; A0.w += m * u.w;
            }
        }
        A0.x += (A1.x + A2.x) + A3.x;
        A0.y += (A1.y + A2.y) + A3.y;
        A0.z += (A1.z + A2.z) + A3.z;
        A0.w += (A1.w + A2.w) + A3.w;
        sY4[b][q] = A0;
        __syncthreads();

#pragma unroll
        for (int bb = 0; bb < BDIM; bb++) {
            const float* yb = (const float*)sY4[bb];
            float z0 = bzo, z1 = bzo, h0 = bho, h1 = bho;
#pragma unroll
            for (int f = 0; f < FDIM; f++) {
                float ya = yb[f * TDIM + t0];
                float yc = yb[f * TDIM + t1];
                z0 += ya * wzr[f]; h0 += ya * whr[f];
                z1 += yc * wzr[f]; h1 += yc * whr[f];
            }
            float contrib = p0 * (1.f - sigm(z0)) * tanhfast(h0)
                          + p1 * (1.f - sigm(z1)) * tanhfast(h1);
            atomicAdd(&sAcc[bb][o], contrib);
        }
        __syncthreads();

        if (tid < BDIM * TDIM) {
            int ob = tid / TDIM, jj = tid - ob * TDIM;
            float v = sBout[jj];
#pragma unroll
            for (int o2 = 0; o2 < ODIM; o2++) {
                v += fmaxf(sAcc[ob][o2], 0.f) * sWout[o2 * TDIM + jj];
            }
            out[(unsigned)(ob * N + n) * TDIM + jj] = v;
        }
        __syncthreads();
    }
}

extern "C" void kernel_launch(void* const* d_in, const int* in_sizes, int n_in,
                              void* d_out, int out_size, void* d_ws, size_t ws_size,
                              hipStream_t stream) {
    const float* X    = (const float*)d_in[0];
    const int*   ei   = (const int*)d_in[1];
    const float* Wg_z = (const float*)d_in[2];
    const float* bg_z = (const float*)d_in[3];
    const float* Wg_h = (const float*)d_in[6];
    const float* bg_h = (const float*)d_in[7];
    const float* Wl_z = (const float*)d_in[8];
    const float* bl_z = (const float*)d_in[9];
    const float* Wl_h = (const float*)d_in[12];
    const float* bl_h = (const float*)d_in[13];
    const float* att  = (const float*)d_in[14];
    const float* Wout = (const float*)d_in[15];
    const float* bout = (const float*)d_in[16];
    float* out = (float*)d_out;

    const int E = in_sizes[1] / 2;
    const int N = in_sizes[0] / (BDIM * FDIM * TDIM);
    const size_t xElems = (size_t)BDIM * N * FDIM * TDIM;
    const size_t xhBytes = xElems * 2;
    const size_t csrBytes = (size_t)(E + N) * 8;
    const size_t restBytes = (size_t)N * 4 * 4 + 4096 + csrBytes + 20000;
    const bool useH = ws_size >= xhBytes + restBytes;
    const int nScanBlk = (N + SCAN_TILE - 1) / SCAN_TILE;

    char* wp = (char*)d_ws;
    uint2* Xh = nullptr;
    if (useH) { Xh = (uint2*)wp; wp += xhBytes; }
    int* counts   = (int*)wp;   wp += (size_t)N * 4;
    int* fill     = (int*)wp;   wp += (size_t)N * 4;
    int* offs     = (int*)wp;   wp += (size_t)(N + 4) * 4;
    float* dis    = (float*)wp; wp += (size_t)N * 4;
    int2* csr     = (int2*)wp;  wp += csrBytes;
    float* Wz     = (float*)wp; wp += FDIM * ODIM * 4;
    float* Wh     = (float*)wp; wp += FDIM * ODIM * 4;
    float* bz     = (float*)wp; wp += ODIM * 4;
    float* bh     = (float*)wp; wp += ODIM * 4;
    float* probs  = (float*)wp; wp += 16 * 4;

    hipMemsetAsync(counts, 0, (size_t)N * 4, stream);

    const int cvtB = useH ? 2048 : 0;
    const int cntB = (E + 255) / 256;
    const int n4 = (int)(xElems / 4);
    kA<<<cvtB + cntB + 1, 256, 0, stream>>>(
        (const float4*)X, Xh, n4, cvtB,
        ei + E, counts, E, cntB,
        Wg_z, bg_z, Wl_z, bl_z, Wg_h, bg_h, Wl_h, bl_h, att,
        Wz, bz, Wh, bh, probs);
    kB<<<nScanBlk, 256, 0, stream>>>(counts, N, offs, dis, fill, csr, E);
    k_scatter<<<(E + 255) / 256, 256, 0, stream>>>(ei, ei + E, offs, fill, dis, csr, E);

    if (useH) {
        k_main_w<<<2048, 256, 0, stream>>>((const uint4*)Xh, offs, csr,
                                           Wz, bz, Wh, bh, probs, Wout, bout, out, N);
    } else {
        int nB = N < 2048 ? N : 2048;
        k_main_f<<<nB, 384, 0, stream>>>(X, offs, csr, dis, Wz, bz, Wh, bh,
                                         probs, Wout, bout, out, N);
    }
}

// Round 17
// 346.936 us; speedup vs baseline: 1.1752x; 1.1752x over previous
//
#include <hip/hip_runtime.h>
#include <hip/hip_bf16.h>
#include <hip/hip_fp16.h>

// TemporalGNN: GRU's H stays zero => R dead, timesteps independent.
// out[b,n,:] = relu( sum_t p_t*(1-Z_t)*Ht_t ) @ W_out + b_out
// R17 = revert k_main_w to the proven R15 version (int2 scalar CSR stream;
// R16's int4 widening added 100MB of L2-miss traffic and cost 65us).
// Keeps the merged single-kernel scan (kB) and fused setup (kA).

#define FDIM 32
#define TDIM 12
#define ODIM 64
#define BDIM 4
#define SCAN_TILE 1024

typedef _Float16 half8v __attribute__((ext_vector_type(8)));
typedef float float4v __attribute__((ext_vector_type(4)));

// ---- fused setup kernel A: [0,cvtB) cvt, [cvtB,cvtB+cntB) count, last prep ----
__global__ __launch_bounds__(256) void kA(
    const float4* __restrict__ Xin, uint2* __restrict__ Xh, int n4, int cvtB,
    const int* __restrict__ dstE, int* __restrict__ counts, int E, int cntB,
    const float* __restrict__ Wg_z, const float* __restrict__ bg_z,
    const float* __restrict__ Wl_z, const float* __restrict__ bl_z,
    const float* __restrict__ Wg_h, const float* __restrict__ bg_h,
    const float* __restrict__ Wl_h, const float* __restrict__ bl_h,
    const float* __restrict__ att,
    float* __restrict__ Wz, float* __restrict__ bz,
    float* __restrict__ Wh, float* __restrict__ bh,
    float* __restrict__ probs) {
    const int bid = blockIdx.x;
    const int tid = threadIdx.x;
    if (bid < cvtB) {
        int i = bid * 256 + tid;
        const int stride = cvtB * 256;
        for (; i < n4; i += stride) {
            const float4 v = Xin[i];
            __half2 h0 = __floats2half2_rn(v.x, v.y);
            __half2 h1 = __floats2half2_rn(v.z, v.w);
            uint2 u;
            u.x = *reinterpret_cast<unsigned*>(&h0);
            u.y = *reinterpret_cast<unsigned*>(&h1);
            Xh[i] = u;
        }
    } else if (bid < cvtB + cntB) {
        int e = (bid - cvtB) * 256 + tid;
        if (e < E) atomicAdd(&counts[dstE[e]], 1);
    } else {
        for (int i = tid; i < FDIM * ODIM; i += 256) {
            int f = i >> 6, o = i & 63;
            float az = 0.f, ah = 0.f;
            for (int k = 0; k < ODIM; k++) {
                az += Wg_z[f * ODIM + k] * Wl_z[k * ODIM + o];
                ah += Wg_h[f * ODIM + k] * Wl_h[k * ODIM + o];
            }
            Wz[i] = az;
            Wh[i] = ah;
        }
        if (tid < ODIM) {
            float az = bl_z[tid], ah = bl_h[tid];
            for (int k = 0; k < ODIM; k++) {
                az += bg_z[k] * Wl_z[k * ODIM + tid];
                ah += bg_h[k] * Wl_h[k * ODIM + tid];
            }
            bz[tid] = az;
            bh[tid] = ah;
        }
        if (tid == 0) {
            float m = -1e30f;
            for (int t = 0; t < TDIM; t++) m = fmaxf(m, att[t]);
            float e[TDIM], s = 0.f;
            for (int t = 0; t < TDIM; t++) { e[t] = expf(att[t] - m); s += e[t]; }
            for (int t = 0; t < TDIM; t++) probs[t] = e[t] / s;
        }
    }
}

// ---- single-pass scan: each block re-reduces all prior tiles itself ----
__global__ __launch_bounds__(256) void kB(const int* __restrict__ counts, int N,
                                          int* __restrict__ offsets,
                                          float* __restrict__ dis,
                                          int* __restrict__ fill,
                                          int2* __restrict__ csr, int E) {
    __shared__ int sBase;
    __shared__ int wsum[4];
    const int tid = threadIdx.x;
    const int blk = blockIdx.x;
    const int lane = tid & 63;
    const int wv = tid >> 6;

    int pre = 0;
    const int preEnd = blk * SCAN_TILE;
    for (int i = tid; i < preEnd; i += 256) pre += counts[i] + 1;
    for (int off = 1; off < 64; off <<= 1) pre += __shfl_xor(pre, off, 64);
    if (lane == 0) wsum[wv] = pre;
    __syncthreads();
    if (tid == 0) sBase = wsum[0] + wsum[1] + wsum[2] + wsum[3];
    __syncthreads();

    const int i0 = blk * SCAN_TILE + tid * 4;
    const int e0 = (i0 + 0 < N) ? counts[i0 + 0] + 1 : 0;
    const int e1 = (i0 + 1 < N) ? counts[i0 + 1] + 1 : 0;
    const int e2 = (i0 + 2 < N) ? counts[i0 + 2] + 1 : 0;
    const int e3 = (i0 + 3 < N) ? counts[i0 + 3] + 1 : 0;
    const int s = e0 + e1 + e2 + e3;
    int inc = s;
    for (int off = 1; off < 64; off <<= 1) {
        int t = __shfl_up(inc, off, 64);
        if (lane >= off) inc += t;
    }
    __syncthreads();
    if (lane == 63) wsum[wv] = inc;
    __syncthreads();
    int wbase = 0;
    for (int j = 0; j < wv; j++) wbase += wsum[j];
    int base = sBase + wbase + inc - s;

    const int ee[4] = {e0, e1, e2, e3};
#pragma unroll
    for (int k = 0; k < 4; k++) {
        const int i = i0 + k;
        if (i < N) {
            offsets[i] = base;
            const float d = 1.0f / sqrtf((float)ee[k]);
            dis[i] = d;
            fill[i] = 1;
            const float nm = d * d;
            __half2 mh = __floats2half2_rn(nm, nm);
            csr[base] = make_int2(i, *(int*)&mh);
            base += ee[k];
        }
    }
    if (blk == 0 && tid == 0) offsets[N] = E + N;
}

__global__ void k_scatter(const int* __restrict__ src, const int* __restrict__ dst,
                          const int* __restrict__ offsets, int* __restrict__ fill,
                          const float* __restrict__ dis,
                          int2* __restrict__ csr, int E) {
    int e = blockIdx.x * 256 + threadIdx.x;
    if (e < E) {
        int s = src[e], d = dst[e];
        int pos = offsets[d] + atomicAdd(&fill[d], 1);
        float nm = dis[s] * dis[d];
        __half2 mh = __floats2half2_rn(nm, nm);
        csr[pos] = make_int2(s, *(int*)&mh);
    }
}

__device__ __forceinline__ float sigm(float x) { return 1.f / (1.f + __expf(-x)); }
__device__ __forceinline__ float tanhfast(float x) { return 1.f - 2.f / (1.f + __expf(2.f * x)); }

#define HPACC(mhI, v, hs0, hs1, hs2, hs3)                                      \
    {                                                                          \
        int mi_ = (mhI);                                                       \
        __half2 mh_ = *(__half2*)&mi_;                                         \
        hs0 = __hfma2(mh_, *(__half2*)&(v).x, hs0);                            \
        hs1 = __hfma2(mh_, *(__half2*)&(v).y, hs1);                            \
        hs2 = __hfma2(mh_, *(__half2*)&(v).z, hs2);                            \
        hs3 = __hfma2(mh_, *(__half2*)&(v).w, hs3);                            \
    }

#define HFLUSH(hs0, hs1, hs2, hs3)                                             \
    {                                                                          \
        float2 t_;                                                             \
        t_ = __half22float2(hs0); a0 += t_.x; a1 += t_.y;                      \
        t_ = __half22float2(hs1); a2 += t_.x; a3 += t_.y;                      \
        t_ = __half22float2(hs2); a4 += t_.x; a5 += t_.y;                      \
        t_ = __half22float2(hs3); a6 += t_.x; a7 += t_.y;                      \
        hs0 = hzero; hs1 = hzero; hs2 = hzero; hs3 = hzero;                    \
    }

#define LOADB(dst, Wsrc, jt)                                                   \
    {                                                                          \
        _Pragma("unroll") for (int r_ = 0; r_ < 8; r_++)                       \
            dst[r_] = (_Float16)Wsrc[(kg * 8 + r_) * ODIM + (jt) * 16 + c];    \
    }

#define EPI(qv, dzv, dhv, bzv, bhv)                                            \
    {                                                                          \
        float s_ = 0.f;                                                        \
        {  const float zf_ = dzv[0] + bzv, hf_ = dhv[0] + bhv;                 \
           const float u_ = __expf(-zf_), v_ = __expf(2.f * hf_);              \
           s_ += pr0 * u_ * (v_ - 1.f) *                                       \
                 __builtin_amdgcn_rcpf((1.f + u_) * (1.f + v_)); }             \
        {  const float zf_ = dzv[1] + bzv, hf_ = dhv[1] + bhv;                 \
           const float u_ = __expf(-zf_), v_ = __expf(2.f * hf_);              \
           s_ += pr1 * u_ * (v_ - 1.f) *                                       \
                 __builtin_amdgcn_rcpf((1.f + u_) * (1.f + v_)); }             \
        {  const float zf_ = dzv[2] + bzv, hf_ = dhv[2] + bhv;                 \
           const float u_ = __expf(-zf_), v_ = __expf(2.f * hf_);              \
           s_ += pr2 * u_ * (v_ - 1.f) *                                       \
                 __builtin_amdgcn_rcpf((1.f + u_) * (1.f + v_)); }             \
        {  const float zf_ = dzv[3] + bzv, hf_ = dhv[3] + bhv;                 \
           const float u_ = __expf(-zf_), v_ = __expf(2.f * hf_);              \
           s_ += pr3 * u_ * (v_ - 1.f) *                                       \
                 __builtin_amdgcn_rcpf((1.f + u_) * (1.f + v_)); }             \
        s_ += __shfl_xor(s_, 16, 64);                                          \
        s_ += __shfl_xor(s_, 32, 64);                                          \
        qv = s_;                                                               \
    }

// Wave-independent main kernel + MFMA gates + MFMA readout + scalar CSR.
// (R15-proven version, unmodified.)
__global__ __launch_bounds__(256, 4) void k_main_w(
    const uint4* __restrict__ Xh, const int* __restrict__ offs,
    const int2* __restrict__ csr,
    const float* __restrict__ Wz, const float* __restrict__ bz,
    const float* __restrict__ Wh, const float* __restrict__ bh,
    const float* __restrict__ probs, const float* __restrict__ Wout,
    const float* __restrict__ bout, float* __restrict__ out, int N) {
    __shared__ float sY[4][16 * 36 + 4];   // [t][f] padded stride 36

    const int tid = threadIdx.x;
    const int wv = tid >> 6;
    const int lane = tid & 63;
    const int lanec = lane < 47 ? lane : 47;
    const int c = lane & 15;
    const int kg = lane >> 4;

    half8v wzf0, wzf1, wzf2, wzf3, whf0, whf1, whf2, whf3;
    LOADB(wzf0, Wz, 0) LOADB(wzf1, Wz, 1) LOADB(wzf2, Wz, 2) LOADB(wzf3, Wz, 3)
    LOADB(whf0, Wh, 0) LOADB(whf1, Wh, 1) LOADB(whf2, Wh, 2) LOADB(whf3, Wh, 3)
    half8v wo0, wo1;
#pragma unroll
    for (int r_ = 0; r_ < 8; r_++) {
        wo0[r_] = (_Float16)((c < TDIM) ? Wout[(kg * 8 + r_) * TDIM + c] : 0.f);
        wo1[r_] = (_Float16)((c < TDIM) ? Wout[(32 + kg * 8 + r_) * TDIM + c] : 0.f);
    }
    const float bz0 = bz[c], bz1 = bz[16 + c], bz2 = bz[32 + c], bz3 = bz[48 + c];
    const float bh0 = bh[c], bh1 = bh[16 + c], bh2 = bh[32 + c], bh3 = bh[48 + c];
    const float pr0 = (kg * 4 + 0 < TDIM) ? probs[kg * 4 + 0] : 0.f;
    const float pr1 = (kg * 4 + 1 < TDIM) ? probs[kg * 4 + 1] : 0.f;
    const float pr2 = (kg * 4 + 2 < TDIM) ? probs[kg * 4 + 2] : 0.f;
    const float pr3 = (kg * 4 + 3 < TDIM) ? probs[kg * 4 + 3] : 0.f;
    const float bo = (lane < TDIM) ? bout[lane] : 0.f;
    const __half2 hzero = __float2half2_rn(0.f);

    float* __restrict__ sy = sY[wv];
    const int strideT = gridDim.x * 4;
    const int totalTasks = N * BDIM;

    int task0 = blockIdx.x * 4 + wv;
    if (task0 >= totalTasks) return;
    int b = task0 / N;
    int n = task0 - b * N;

    while (true) {
        const int bs = __builtin_amdgcn_readfirstlane(b);
        const int ns = __builtin_amdgcn_readfirstlane(n);
        const unsigned rowB = (unsigned)bs * (unsigned)N;
        const int begS = __builtin_amdgcn_readfirstlane(offs[ns]);
        const int endS = __builtin_amdgcn_readfirstlane(offs[ns + 1]);

        // ---- gather: scalar edge stream, fp16 packed accumulate ----
        float a0 = 0.f, a1 = 0.f, a2 = 0.f, a3 = 0.f,
              a4 = 0.f, a5 = 0.f, a6 = 0.f, a7 = 0.f;
        __half2 hA0 = hzero, hA1 = hzero, hA2 = hzero, hA3 = hzero;
        __half2 hB0 = hzero, hB1 = hzero, hB2 = hzero, hB3 = hzero;
        int j = begS;
        for (; j + 8 <= endS; j += 8) {
            const int2 e0 = csr[j + 0], e1 = csr[j + 1], e2 = csr[j + 2], e3 = csr[j + 3];
            const int2 e4 = csr[j + 4], e5 = csr[j + 5], e6 = csr[j + 6], e7 = csr[j + 7];
            const uint4 x0 = Xh[(rowB + (unsigned)e0.x) * 48u + lanec];
            const uint4 x1 = Xh[(rowB + (unsigned)e1.x) * 48u + lanec];
            const uint4 x2 = Xh[(rowB + (unsigned)e2.x) * 48u + lanec];
            const uint4 x3 = Xh[(rowB + (unsigned)e3.x) * 48u + lanec];
            const uint4 x4 = Xh[(rowB + (unsigned)e4.x) * 48u + lanec];
            const uint4 x5 = Xh[(rowB + (unsigned)e5.x) * 48u + lanec];
            const uint4 x6 = Xh[(rowB + (unsigned)e6.x) * 48u + lanec];
            const uint4 x7 = Xh[(rowB + (unsigned)e7.x) * 48u + lanec];
            HPACC(e0.y, x0, hA0, hA1, hA2, hA3);
            HPACC(e1.y, x1, hA0, hA1, hA2, hA3);
            HPACC(e2.y, x2, hA0, hA1, hA2, hA3);
            HPACC(e3.y, x3, hA0, hA1, hA2, hA3);
            HPACC(e4.y, x4, hB0, hB1, hB2, hB3);
            HPACC(e5.y, x5, hB0, hB1, hB2, hB3);
            HPACC(e6.y, x6, hB0, hB1, hB2, hB3);
            HPACC(e7.y, x7, hB0, hB1, hB2, hB3);
            HFLUSH(hA0, hA1, hA2, hA3);
            HFLUSH(hB0, hB1, hB2, hB3);
        }
        for (; j < endS; ++j) {
            const int2 e = csr[j];
            const uint4 xv = Xh[(rowB + (unsigned)e.x) * 48u + lanec];
            HPACC(e.y, xv, hA0, hA1, hA2, hA3);
        }
        HFLUSH(hA0, hA1, hA2, hA3);

        // ---- deposit Y to LDS transposed [t][f] (stride 36) ----
        if (lane < 48) {
            int flat = lane * 8;               // = f*12 + t
            int f = flat / 12;
            int t = flat - f * 12;
#pragma unroll
            for (int k = 0; k < 8; k++) {
                float av = (k == 0) ? a0 : (k == 1) ? a1 : (k == 2) ? a2 :
                           (k == 3) ? a3 : (k == 4) ? a4 : (k == 5) ? a5 :
                           (k == 6) ? a6 : a7;
                sy[t * 36 + f] = av;
                t++;
                if (t == TDIM) { t = 0; f++; }
            }
        }

        // ---- A-frag: row=c (t), k=kg*8+j (f) ----
        half8v af;
        if (c < TDIM) {
            const float4* yp = (const float4*)&sy[c * 36 + kg * 8];
            const float4 y0 = yp[0];
            const float4 y1 = yp[1];
            af[0] = (_Float16)y0.x; af[1] = (_Float16)y0.y;
            af[2] = (_Float16)y0.z; af[3] = (_Float16)y0.w;
            af[4] = (_Float16)y1.x; af[5] = (_Float16)y1.y;
            af[6] = (_Float16)y1.z; af[7] = (_Float16)y1.w;
        } else {
            af[0] = (_Float16)0.f; af[1] = (_Float16)0.f;
            af[2] = (_Float16)0.f; af[3] = (_Float16)0.f;
            af[4] = (_Float16)0.f; af[5] = (_Float16)0.f;
            af[6] = (_Float16)0.f; af[7] = (_Float16)0.f;
        }

        // ---- gates via MFMA ----
        const float4v zero4 = {0.f, 0.f, 0.f, 0.f};
        float4v dz0 = __builtin_amdgcn_mfma_f32_16x16x32_f16(af, wzf0, zero4, 0, 0, 0);
        float4v dz1 = __builtin_amdgcn_mfma_f32_16x16x32_f16(af, wzf1, zero4, 0, 0, 0);
        float4v dz2 = __builtin_amdgcn_mfma_f32_16x16x32_f16(af, wzf2, zero4, 0, 0, 0);
        float4v dz3 = __builtin_amdgcn_mfma_f32_16x16x32_f16(af, wzf3, zero4, 0, 0, 0);
        float4v dh0 = __builtin_amdgcn_mfma_f32_16x16x32_f16(af, whf0, zero4, 0, 0, 0);
        float4v dh1 = __builtin_amdgcn_mfma_f32_16x16x32_f16(af, whf1, zero4, 0, 0, 0);
        float4v dh2 = __builtin_amdgcn_mfma_f32_16x16x32_f16(af, whf2, zero4, 0, 0, 0);
        float4v dh3 = __builtin_amdgcn_mfma_f32_16x16x32_f16(af, whf3, zero4, 0, 0, 0);

        // ---- epilogue: per-o weighted gate sum ----
        float q0, q1, q2, q3;
        EPI(q0, dz0, dh0, bz0, bh0)
        EPI(q1, dz1, dh1, bz1, bh1)
        EPI(q2, dz2, dh2, bz2, bh2)
        EPI(q3, dz3, dh3, bz3, bh3)
        const float accOwn = (kg == 0) ? q0 : (kg == 1) ? q1 : (kg == 2) ? q2 : q3;

        // ---- readout GEMV on MFMA ----
        const float r = fmaxf(accOwn, 0.f);
        half8v ra0, ra1;
#pragma unroll
        for (int j2 = 0; j2 < 8; j2++) {
            ra0[j2] = (_Float16)__shfl(r, (kg << 3) + j2, 64);
            ra1[j2] = (_Float16)__shfl(r, 32 + (kg << 3) + j2, 64);
        }
        float4v dro = __builtin_amdgcn_mfma_f32_16x16x32_f16(ra0, wo0, zero4, 0, 0, 0);
        dro = __builtin_amdgcn_mfma_f32_16x16x32_f16(ra1, wo1, dro, 0, 0, 0);
        if (lane < TDIM)
            out[(rowB + (unsigned)n) * TDIM + lane] = dro[0] + bo;

        // ---- advance task ----
        n += strideT;
        if (n >= N) { n -= N; b++; }
        if (b >= BDIM) break;
    }
}

// fp32 fallback (no fp16 workspace): consumes self-inclusive csr (half2 norms).
__global__ __launch_bounds__(384) void k_main_f(
    const float* __restrict__ X, const int* __restrict__ offsets,
    const int2* __restrict__ csr, const float* __restrict__ dis,
    const float* __restrict__ Wz, const float* __restrict__ bz,
    const float* __restrict__ Wh, const float* __restrict__ bh,
    const float* __restrict__ probs, const float* __restrict__ Wout,
    const float* __restrict__ bout, float* __restrict__ out, int N) {
    const int tid = threadIdx.x;
    const int lane = tid & 63;

    __shared__ float4 sY4[BDIM][96];
    __shared__ float sAcc[BDIM][ODIM];
    __shared__ float sWout[ODIM * TDIM];
    __shared__ float sBout[TDIM];

    for (int i = tid; i < ODIM * TDIM; i += 384) sWout[i] = Wout[i];
    if (tid < TDIM) sBout[tid] = bout[tid];

    const int o = tid & 63;
    const int w = tid >> 6;
    float wzr[FDIM], whr[FDIM];
#pragma unroll
    for (int f = 0; f < FDIM; f++) {
        wzr[f] = Wz[f * ODIM + o];
        whr[f] = Wh[f * ODIM + o];
    }
    const float bzo = bz[o], bho = bh[o];
    const int t0 = w, t1 = w + 6;
    const float p0 = probs[t0], p1 = probs[t1];

    const int b = tid / 96;
    const int q = tid - b * 96;
    const float4* __restrict__ Xq = (const float4*)X;
    const unsigned rowBase = (unsigned)b * (unsigned)N;

    for (int n = blockIdx.x; n < N; n += gridDim.x) {
        if (tid < BDIM * ODIM) ((float*)sAcc)[tid] = 0.f;

        const int beg = offsets[n], end = offsets[n + 1];
        float4 A0 = make_float4(0.f, 0.f, 0.f, 0.f);
        float4 A1 = A0, A2 = A0, A3 = A0;

        for (int ebase = beg; ebase < end; ebase += 64) {
            const int cnt2 = min(64, end - ebase);
            int esrc = 0;
            float enm = 0.f;
            if (ebase + lane < end) {
                const int2 e = csr[ebase + lane];
                esrc = e.x;
                int ey = e.y;
                enm = __half22float2(*(__half2*)&ey).x;
            }
            int j = 0;
            for (; j + 4 <= cnt2; j += 4) {
                const int s0 = __shfl(esrc, j + 0, 64), s1 = __shfl(esrc, j + 1, 64);
                const int s2 = __shfl(esrc, j + 2, 64), s3 = __shfl(esrc, j + 3, 64);
                const float m0 = __shfl(enm, j + 0, 64), m1 = __shfl(enm, j + 1, 64);
                const float m2 = __shfl(enm, j + 2, 64), m3 = __shfl(enm, j + 3, 64);
                const float4 u0 = Xq[(rowBase + s0) * 96u + q];
                const float4 u1 = Xq[(rowBase + s1) * 96u + q];
                const float4 u2 = Xq[(rowBase + s2) * 96u + q];
                const float4 u3 = Xq[(rowBase + s3) * 96u + q];
                A0.x += m0 * u0.x; A0.y += m0 * u0.y; A0.z += m0 * u0.z; A0.w += m0 * u0.w;
                A1.x += m1 * u1.x; A1.y += m1 * u1.y; A1.z += m1 * u1.z; A1.w += m1 * u1.w;
                A2.x += m2 * u2.x; A2.y += m2 * u2.y; A2.z += m2 * u2.z; A2.w += m2 * u2.w;
                A3.x += m3 * u3.x; A3.y += m3 * u3.y; A3.z += m3 * u3.z; A3.w += m3 * u3.w;
            }
            for (; j < cnt2; j++) {
                const int s = __shfl(esrc, j, 64);
                const float m = __shfl(enm, j, 64);
                const float4 u = Xq[(rowBase + s) * 96u + q];
                A0.x += m * u.x; A0.y += m * u.y; A0.z += m * u.z; A0.w += m * u.w;
            }
        }
        A0.x += (A1.x + A2.x) + A3.x;
        A0.y += (A1.y + A2.y) + A3.y;
        A0.z += (A1.z + A2.z) + A3.z;
        A0.w += (A1.w + A2.w) + A3.w;
        sY4[b][q] = A0;
        __syncthreads();

#pragma unroll
        for (int bb = 0; bb < BDIM; bb++) {
            const float* yb = (const float*)sY4[bb];
            float z0 = bzo, z1 = bzo, h0 = bho, h1 = bho;
#pragma unroll
            for (int f = 0; f < FDIM; f++) {
                float ya = yb[f * TDIM + t0];
                float yc = yb[f * TDIM + t1];
                z0 += ya * wzr[f]; h0 += ya * whr[f];
                z1 += yc * wzr[f]; h1 += yc * whr[f];
            }
            float contrib = p0 * (1.f - sigm(z0)) * tanhfast(h0)
                          + p1 * (1.f - sigm(z1)) * tanhfast(h1);
            atomicAdd(&sAcc[bb][o], contrib);
        }
        __syncthreads();

        if (tid < BDIM * TDIM) {
            int ob = tid / TDIM, jj = tid - ob * TDIM;
            float v = sBout[jj];
#pragma unroll
            for (int o2 = 0; o2 < ODIM; o2++) {
                v += fmaxf(sAcc[ob][o2], 0.f) * sWout[o2 * TDIM + jj];
            }
            out[(unsigned)(ob * N + n) * TDIM + jj] = v;
        }
        __syncthreads();
    }
}

extern "C" void kernel_launch(void* const* d_in, const int* in_sizes, int n_in,
                              void* d_out, int out_size, void* d_ws, size_t ws_size,
                              hipStream_t stream) {
    const float* X    = (const float*)d_in[0];
    const int*   ei   = (const int*)d_in[1];
    const float* Wg_z = (const float*)d_in[2];
    const float* bg_z = (const float*)d_in[3];
    const float* Wg_h = (const float*)d_in[6];
    const float* bg_h = (const float*)d_in[7];
    const float* Wl_z = (const float*)d_in[8];
    const float* bl_z = (const float*)d_in[9];
    const float* Wl_h = (const float*)d_in[12];
    const float* bl_h = (const float*)d_in[13];
    const float* att  = (const float*)d_in[14];
    const float* Wout = (const float*)d_in[15];
    const float* bout = (const float*)d_in[16];
    float* out = (float*)d_out;

    const int E = in_sizes[1] / 2;
    const int N = in_sizes[0] / (BDIM * FDIM * TDIM);
    const size_t xElems = (size_t)BDIM * N * FDIM * TDIM;
    const size_t xhBytes = xElems * 2;
    const size_t csrBytes = (size_t)(E + N) * 8;
    const size_t restBytes = (size_t)N * 4 * 4 + 4096 + csrBytes + 20000;
    const bool useH = ws_size >= xhBytes + restBytes;
    const int nScanBlk = (N + SCAN_TILE - 1) / SCAN_TILE;

    char* wp = (char*)d_ws;
    uint2* Xh = nullptr;
    if (useH) { Xh = (uint2*)wp; wp += xhBytes; }
    int* counts   = (int*)wp;   wp += (size_t)N * 4;
    int* fill     = (int*)wp;   wp += (size_t)N * 4;
    int* offs     = (int*)wp;   wp += (size_t)(N + 4) * 4;
    float* dis    = (float*)wp; wp += (size_t)N * 4;
    int2* csr     = (int2*)wp;  wp += csrBytes;
    float* Wz     = (float*)wp; wp += FDIM * ODIM * 4;
    float* Wh     = (float*)wp; wp += FDIM * ODIM * 4;
    float* bz     = (float*)wp; wp += ODIM * 4;
    float* bh     = (float*)wp; wp += ODIM * 4;
    float* probs  = (float*)wp; wp += 16 * 4;

    hipMemsetAsync(counts, 0, (size_t)N * 4, stream);

    const int cvtB = useH ? 2048 : 0;
    const int cntB = (E + 255) / 256;
    const int n4 = (int)(xElems / 4);
    kA<<<cvtB + cntB + 1, 256, 0, stream>>>(
        (const float4*)X, Xh, n4, cvtB,
        ei + E, counts, E, cntB,
        Wg_z, bg_z, Wl_z, bl_z, Wg_h, bg_h, Wl_h, bl_h, att,
        Wz, bz, Wh, bh, probs);
    kB<<<nScanBlk, 256, 0, stream>>>(counts, N, offs, dis, fill, csr, E);
    k_scatter<<<(E + 255) / 256, 256, 0, stream>>>(ei, ei + E, offs, fill, dis, csr, E);

    if (useH) {
        k_main_w<<<2048, 256, 0, stream>>>((const uint4*)Xh, offs, csr,
                                           Wz, bz, Wh, bh, probs, Wout, bout, out, N);
    } else {
        int nB = N < 2048 ? N : 2048;
        k_main_f<<<nB, 384, 0, stream>>>(X, offs, csr, dis, Wz, bz, Wh, bh,
                                         probs, Wout, bout, out, N);
    }
}